// Round 1
// 651.117 us; speedup vs baseline: 1.0164x; 1.0164x over previous
//
#include <hip/hip_runtime.h>

typedef __bf16 bf16;
typedef bf16 bf16x8 __attribute__((ext_vector_type(8)));
typedef float f32x4 __attribute__((ext_vector_type(4)));

#define LD64  80   // padded LDS row stride (elems) for 64-wide tiles: 160B, 16B-aligned
#define LD128 144  // padded LDS row stride for 128-wide tiles: 288B, 16B-aligned

// Barrier that drains ONLY lgkmcnt (LDS visibility). Crucially does NOT drain
// vmcnt, so outstanding fire-and-forget atomics and prefetch loads stay in
// flight across the barrier (unlike __syncthreads, which the compiler lowers
// with a full s_waitcnt vmcnt(0) lgkmcnt(0)).
#define BAR_LGKM() asm volatile("s_waitcnt lgkmcnt(0)\n\ts_barrier" ::: "memory")

static __device__ __forceinline__ f32x4 mfma16(bf16x8 a, bf16x8 b, f32x4 c) {
    return __builtin_amdgcn_mfma_f32_16x16x32_bf16(a, b, c, 0, 0, 0);
}

static __device__ __forceinline__ bf16x8 cvt8(float4 a, float4 b) {
    bf16x8 v;
    v[0] = (bf16)a.x; v[1] = (bf16)a.y; v[2] = (bf16)a.z; v[3] = (bf16)a.w;
    v[4] = (bf16)b.x; v[5] = (bf16)b.y; v[6] = (bf16)b.z; v[7] = (bf16)b.w;
    return v;
}

// ---------------------------------------------------------------------------
// rel1: m = relu(emb[idx] @ W1 + b1) @ W2 + b2 ; atomicAdd into agg[idx]
// Depth-2 pipelined: emb rows for tile t+1 prefetched into registers and idx
// for tile t+2 in flight while tile t computes. 2 lgkm-only barriers/iter.
// ---------------------------------------------------------------------------
__global__ __launch_bounds__(256) void rel1_kernel(
    const float* __restrict__ emb, const int* __restrict__ idx,
    const float* __restrict__ W1, const float* __restrict__ b1,
    const float* __restrict__ W2, const float* __restrict__ b2,
    float* __restrict__ agg, int M, int numTiles)
{
    __shared__ bf16 sW1t[64 * LD64];   // [n][k]
    __shared__ bf16 sW2t[64 * LD64];
    __shared__ bf16 sG[64 * LD64];
    __shared__ bf16 sH[64 * LD64];
    __shared__ float sB1[64], sB2[64];
    __shared__ int sIdx[2][64];        // double-buffered scatter ids

    const int t = threadIdx.x;
    const int wave = t >> 6, lane = t & 63;
    const int l15 = lane & 15, quad = lane >> 4;
    const int r = t >> 2, p = t & 3;   // 4 threads per gathered row
    const int stride = gridDim.x;

    for (int i = t; i < 64 * 64; i += 256) {
        int k = i >> 6, n = i & 63;
        sW1t[n * LD64 + k] = (bf16)W1[i];
        sW2t[n * LD64 + k] = (bf16)W2[i];
    }
    if (t < 64) { sB1[t] = b1[t]; sB2[t] = b2[t]; }

    int tile = blockIdx.x;

    // prologue: emb prefetch for tile, idx prefetch for tile+stride
    int idW = -1;
    { int R = tile * 64 + r; if (tile < numTiles && R < M) idW = idx[R]; }
    float4 pf[4];
    if (idW >= 0) {
        const float4* src = (const float4*)(emb + (size_t)idW * 64 + p * 16);
        #pragma unroll
        for (int i = 0; i < 4; ++i) pf[i] = src[i];
    }
    int idN = -1;
    { int nt = tile + stride; if (nt < numTiles) { int R = nt * 64 + r; if (R < M) idN = idx[R]; } }

    int buf = 0;
    while (tile < numTiles) {
        // A: stage current tile (registers -> LDS, vectorized b128 stores)
        if (p == 0) sIdx[buf][r] = idW;
        if (idW >= 0) {
            #pragma unroll
            for (int i = 0; i < 2; ++i)
                *(bf16x8*)&sG[r * LD64 + p * 16 + i * 8] = cvt8(pf[2 * i], pf[2 * i + 1]);
        }
        BAR_LGKM();

        // C: issue next tile's prefetch BEFORE this tile's atomics, so the
        // next iteration's ds_write dependency wait skips over the atomics.
        const int tile1 = tile + stride;
        idW = idN;
        if (tile1 < numTiles && idW >= 0) {
            const float4* src = (const float4*)(emb + (size_t)idW * 64 + p * 16);
            #pragma unroll
            for (int i = 0; i < 4; ++i) pf[i] = src[i];
        }
        idN = -1;
        { int nt = tile1 + stride; if (nt < numTiles) { int R = nt * 64 + r; if (R < M) idN = idx[R]; } }

        // D: GEMM1: h = relu(g @ W1 + b1)
        f32x4 acc[4];
        #pragma unroll
        for (int nt = 0; nt < 4; ++nt) acc[nt] = (f32x4){0.f, 0.f, 0.f, 0.f};
        #pragma unroll
        for (int kt = 0; kt < 2; ++kt) {
            bf16x8 a = *(const bf16x8*)&sG[(wave * 16 + l15) * LD64 + kt * 32 + quad * 8];
            #pragma unroll
            for (int nt = 0; nt < 4; ++nt) {
                bf16x8 bfr = *(const bf16x8*)&sW1t[(nt * 16 + l15) * LD64 + kt * 32 + quad * 8];
                acc[nt] = mfma16(a, bfr, acc[nt]);
            }
        }
        #pragma unroll
        for (int nt = 0; nt < 4; ++nt) {
            float bias = sB1[nt * 16 + l15];
            #pragma unroll
            for (int rr = 0; rr < 4; ++rr) {
                float v = acc[nt][rr] + bias;
                v = v > 0.f ? v : 0.f;
                sH[(wave * 16 + quad * 4 + rr) * LD64 + nt * 16 + l15] = (bf16)v;
            }
        }
        BAR_LGKM();

        // F/G: GEMM2 + fire-and-forget scatter
        f32x4 acc2[4];
        #pragma unroll
        for (int nt = 0; nt < 4; ++nt) acc2[nt] = (f32x4){0.f, 0.f, 0.f, 0.f};
        #pragma unroll
        for (int kt = 0; kt < 2; ++kt) {
            bf16x8 a = *(const bf16x8*)&sH[(wave * 16 + l15) * LD64 + kt * 32 + quad * 8];
            #pragma unroll
            for (int nt = 0; nt < 4; ++nt) {
                bf16x8 bfr = *(const bf16x8*)&sW2t[(nt * 16 + l15) * LD64 + kt * 32 + quad * 8];
                acc2[nt] = mfma16(a, bfr, acc2[nt]);
            }
        }
        #pragma unroll
        for (int nt = 0; nt < 4; ++nt) {
            float bias = sB2[nt * 16 + l15];
            #pragma unroll
            for (int rr = 0; rr < 4; ++rr) {
                int row = wave * 16 + quad * 4 + rr;
                int id = sIdx[buf][row];
                if (id >= 0)
                    atomicAdd(&agg[(size_t)id * 64 + nt * 16 + l15], acc2[nt][rr] + bias);
            }
        }
        buf ^= 1;
        tile = tile1;
    }
}

// ---------------------------------------------------------------------------
// rel2: g = [emb[i0]||emb[i1]] (128); m = relu(g@W1+b1)@W2+b2 (128);
// cols 0..63 scatter to i0, 64..127 to i1. Same depth-2 pipeline; W1/W2
// B-fragments in registers.
// ---------------------------------------------------------------------------
__global__ __launch_bounds__(256) void rel2_kernel(
    const float* __restrict__ emb, const int* __restrict__ idx,  // [M][2]
    const float* __restrict__ W1, const float* __restrict__ b1,  // 128x128, 128
    const float* __restrict__ W2, const float* __restrict__ b2,
    float* __restrict__ agg, int M, int numTiles)
{
    __shared__ bf16 sG[64 * LD128];
    __shared__ bf16 sH[64 * LD128];
    __shared__ int sIdx[2][128];

    const int t = threadIdx.x;
    const int wave = t >> 6, lane = t & 63;
    const int l15 = lane & 15, quad = lane >> 4;
    const int r = t >> 2, p = t & 3;   // 4 threads per row, 32 floats each
    const int stride = gridDim.x;

    // per-wave B fragments in registers: n-tiles {2*wave, 2*wave+1}
    bf16x8 w1f[2][4], w2f[2][4];
    float bias1[2], bias2[2];
    #pragma unroll
    for (int j = 0; j < 2; ++j) {
        const int n = (wave * 2 + j) * 16 + l15;
        bias1[j] = b1[n];
        bias2[j] = b2[n];
        #pragma unroll
        for (int kt = 0; kt < 4; ++kt) {
            bf16x8 f1, f2;
            #pragma unroll
            for (int e = 0; e < 8; ++e) {
                int k = kt * 32 + quad * 8 + e;
                f1[e] = (bf16)W1[k * 128 + n];
                f2[e] = (bf16)W2[k * 128 + n];
            }
            w1f[j][kt] = f1;
            w2f[j][kt] = f2;
        }
    }

    int tile = blockIdx.x;

    // prologue prefetch
    int idA = -1, idB = -1;
    if (tile < numTiles) {
        int R = tile * 64 + r;
        if (R < M) { idA = idx[R * 2]; idB = idx[R * 2 + 1]; }
    }
    float4 pf[8];
    {
        int myid = (p < 2) ? idA : idB;
        if (myid >= 0) {
            const float4* src = (const float4*)(emb + (size_t)myid * 64 + (p & 1) * 32);
            #pragma unroll
            for (int i = 0; i < 8; ++i) pf[i] = src[i];
        }
    }
    int nA = -1, nB = -1;
    { int nt = tile + stride; if (nt < numTiles) { int R = nt * 64 + r; if (R < M) { nA = idx[R * 2]; nB = idx[R * 2 + 1]; } } }

    int buf = 0;
    while (tile < numTiles) {
        // A: stage current tile
        if (p == 0) { sIdx[buf][r * 2] = idA; sIdx[buf][r * 2 + 1] = idB; }
        if (((p < 2) ? idA : idB) >= 0) {
            #pragma unroll
            for (int i = 0; i < 4; ++i)
                *(bf16x8*)&sG[r * LD128 + p * 32 + i * 8] = cvt8(pf[2 * i], pf[2 * i + 1]);
        }
        BAR_LGKM();

        // C: prefetch next tile (issued before this tile's atomics)
        const int tile1 = tile + stride;
        idA = nA; idB = nB;
        {
            int myid = (p < 2) ? idA : idB;
            if (tile1 < numTiles && myid >= 0) {
                const float4* src = (const float4*)(emb + (size_t)myid * 64 + (p & 1) * 32);
                #pragma unroll
                for (int i = 0; i < 8; ++i) pf[i] = src[i];
            }
        }
        nA = -1; nB = -1;
        { int nt = tile1 + stride; if (nt < numTiles) { int R = nt * 64 + r; if (R < M) { nA = idx[R * 2]; nB = idx[R * 2 + 1]; } } }

        // D: GEMM1 over all 4 m-tiles, this wave's 2 n-tiles
        f32x4 acc[4][2];
        #pragma unroll
        for (int mt = 0; mt < 4; ++mt)
            #pragma unroll
            for (int j = 0; j < 2; ++j) acc[mt][j] = (f32x4){0.f, 0.f, 0.f, 0.f};
        #pragma unroll
        for (int mt = 0; mt < 4; ++mt) {
            #pragma unroll
            for (int kt = 0; kt < 4; ++kt) {
                bf16x8 a = *(const bf16x8*)&sG[(mt * 16 + l15) * LD128 + kt * 32 + quad * 8];
                #pragma unroll
                for (int j = 0; j < 2; ++j) acc[mt][j] = mfma16(a, w1f[j][kt], acc[mt][j]);
            }
        }
        #pragma unroll
        for (int mt = 0; mt < 4; ++mt)
            #pragma unroll
            for (int j = 0; j < 2; ++j) {
                #pragma unroll
                for (int rr = 0; rr < 4; ++rr) {
                    float v = acc[mt][j][rr] + bias1[j];
                    v = v > 0.f ? v : 0.f;
                    sH[(mt * 16 + quad * 4 + rr) * LD128 + (wave * 2 + j) * 16 + l15] = (bf16)v;
                }
            }
        BAR_LGKM();

        // F: GEMM2
        f32x4 acc2[4][2];
        #pragma unroll
        for (int mt = 0; mt < 4; ++mt)
            #pragma unroll
            for (int j = 0; j < 2; ++j) acc2[mt][j] = (f32x4){0.f, 0.f, 0.f, 0.f};
        #pragma unroll
        for (int mt = 0; mt < 4; ++mt) {
            #pragma unroll
            for (int kt = 0; kt < 4; ++kt) {
                bf16x8 a = *(const bf16x8*)&sH[(mt * 16 + l15) * LD128 + kt * 32 + quad * 8];
                #pragma unroll
                for (int j = 0; j < 2; ++j) acc2[mt][j] = mfma16(a, w2f[j][kt], acc2[mt][j]);
            }
        }
        // G: scatter, fire-and-forget: col<64 -> arg0 node, col>=64 -> arg1
        #pragma unroll
        for (int mt = 0; mt < 4; ++mt) {
            #pragma unroll
            for (int j = 0; j < 2; ++j) {
                const int col = (wave * 2 + j) * 16 + l15;
                const int sel = col >> 6;
                const int c = col & 63;
                #pragma unroll
                for (int rr = 0; rr < 4; ++rr) {
                    int row = mt * 16 + quad * 4 + rr;
                    int id = sIdx[buf][row * 2 + sel];
                    if (id >= 0)
                        atomicAdd(&agg[(size_t)id * 64 + c], acc2[mt][j][rr] + bias2[j]);
                }
            }
        }
        buf ^= 1;
        tile = tile1;
    }
}

// ---------------------------------------------------------------------------
// update: out = relu([emb||agg] @ W1 + b1) @ W2 + b2
// ---------------------------------------------------------------------------
__global__ __launch_bounds__(256) void update_kernel(
    const float* __restrict__ emb, const float* __restrict__ agg,
    const float* __restrict__ W1, const float* __restrict__ b1,  // 128x64, 64
    const float* __restrict__ W2, const float* __restrict__ b2,  // 64x64, 64
    float* __restrict__ out, int N, int numTiles)
{
    __shared__ bf16 sW1t[64 * LD128];  // [n][k], k=128
    __shared__ bf16 sW2t[64 * LD64];   // [n][k], k=64
    __shared__ bf16 sU[64 * LD128];
    __shared__ bf16 sH[64 * LD64];
    __shared__ float sB1[64], sB2[64];

    const int t = threadIdx.x;
    const int wave = t >> 6, lane = t & 63;
    const int l15 = lane & 15, quad = lane >> 4;
    const int r = t >> 2, p = t & 3;

    for (int i = t; i < 128 * 64; i += 256) {
        int k = i >> 6, n = i & 63;
        sW1t[n * LD128 + k] = (bf16)W1[i];
    }
    for (int i = t; i < 64 * 64; i += 256) {
        int k = i >> 6, n = i & 63;
        sW2t[n * LD64 + k] = (bf16)W2[i];
    }
    if (t < 64) { sB1[t] = b1[t]; sB2[t] = b2[t]; }

    for (int tile = blockIdx.x; tile < numTiles; tile += gridDim.x) {
        const int base = tile * 64;
        {   // gather u = [emb row || agg row], vectorized staging
            const int R = base + r;
            if (R < N) {
                const float* srcp = (p < 2) ? (emb + (size_t)R * 64 + p * 32)
                                            : (agg + (size_t)R * 64 + (p - 2) * 32);
                const float4* src = (const float4*)srcp;
                #pragma unroll
                for (int i = 0; i < 4; ++i)
                    *(bf16x8*)&sU[r * LD128 + p * 32 + i * 8] = cvt8(src[2 * i], src[2 * i + 1]);
            }
        }
        BAR_LGKM();

        // GEMM1: K=128 -> 4 k-steps, N=64 -> 4 n-tiles
        f32x4 acc[4];
        #pragma unroll
        for (int nt = 0; nt < 4; ++nt) acc[nt] = (f32x4){0.f, 0.f, 0.f, 0.f};
        #pragma unroll
        for (int kt = 0; kt < 4; ++kt) {
            bf16x8 a = *(const bf16x8*)&sU[(wave * 16 + l15) * LD128 + kt * 32 + quad * 8];
            #pragma unroll
            for (int nt = 0; nt < 4; ++nt) {
                bf16x8 bfr = *(const bf16x8*)&sW1t[(nt * 16 + l15) * LD128 + kt * 32 + quad * 8];
                acc[nt] = mfma16(a, bfr, acc[nt]);
            }
        }
        #pragma unroll
        for (int nt = 0; nt < 4; ++nt) {
            float bias = sB1[nt * 16 + l15];
            #pragma unroll
            for (int rr = 0; rr < 4; ++rr) {
                float v = acc[nt][rr] + bias;
                v = v > 0.f ? v : 0.f;
                sH[(wave * 16 + quad * 4 + rr) * LD64 + nt * 16 + l15] = (bf16)v;
            }
        }
        BAR_LGKM();

        // GEMM2: K=64
        f32x4 acc2[4];
        #pragma unroll
        for (int nt = 0; nt < 4; ++nt) acc2[nt] = (f32x4){0.f, 0.f, 0.f, 0.f};
        #pragma unroll
        for (int kt = 0; kt < 2; ++kt) {
            bf16x8 a = *(const bf16x8*)&sH[(wave * 16 + l15) * LD64 + kt * 32 + quad * 8];
            #pragma unroll
            for (int nt = 0; nt < 4; ++nt) {
                bf16x8 bfr = *(const bf16x8*)&sW2t[(nt * 16 + l15) * LD64 + kt * 32 + quad * 8];
                acc2[nt] = mfma16(a, bfr, acc2[nt]);
            }
        }
        #pragma unroll
        for (int nt = 0; nt < 4; ++nt) {
            float bias = sB2[nt * 16 + l15];
            #pragma unroll
            for (int rr = 0; rr < 4; ++rr) {
                int row = wave * 16 + quad * 4 + rr;
                int R = base + row;
                if (R < N)
                    out[(size_t)R * 64 + nt * 16 + l15] = acc2[nt][rr] + bias;
            }
        }
    }
}

extern "C" void kernel_launch(void* const* d_in, const int* in_sizes, int n_in,
                              void* d_out, int out_size, void* d_ws, size_t ws_size,
                              hipStream_t stream) {
    const float* emb    = (const float*)d_in[0];
    const int*   rel1   = (const int*)d_in[1];
    const int*   rel2   = (const int*)d_in[2];
    const float* m1W1   = (const float*)d_in[3];
    const float* m1b1   = (const float*)d_in[4];
    const float* m1W2   = (const float*)d_in[5];
    const float* m1b2   = (const float*)d_in[6];
    const float* m2W1   = (const float*)d_in[7];
    const float* m2b1   = (const float*)d_in[8];
    const float* m2W2   = (const float*)d_in[9];
    const float* m2b2   = (const float*)d_in[10];
    const float* uW1    = (const float*)d_in[11];
    const float* ub1    = (const float*)d_in[12];
    const float* uW2    = (const float*)d_in[13];
    const float* ub2    = (const float*)d_in[14];

    const int N  = in_sizes[0] / 64;   // 100000
    const int M1 = in_sizes[1];        // 500000
    const int M2 = in_sizes[2] / 2;    // 1000000
    float* agg = (float*)d_ws;         // [N][64]

    hipMemsetAsync(agg, 0, (size_t)N * 64 * sizeof(float), stream);

    const int t1 = (M1 + 63) / 64;
    const int g1 = t1 < 1024 ? t1 : 1024;
    rel1_kernel<<<g1, 256, 0, stream>>>(emb, rel1, m1W1, m1b1, m1W2, m1b2, agg, M1, t1);

    const int t2 = (M2 + 63) / 64;
    const int g2 = t2 < 2048 ? t2 : 2048;
    rel2_kernel<<<g2, 256, 0, stream>>>(emb, rel2, m2W1, m2b1, m2W2, m2b2, agg, M2, t2);

    const int tu = (N + 63) / 64;
    update_kernel<<<tu, 256, 0, stream>>>(emb, agg, uW1, ub1, uW2, ub2, (float*)d_out, N, tu);
}